// Round 7
// baseline (396.554 us; speedup 1.0000x reference)
//
#include <hip/hip_runtime.h>

// ---------------------------------------------------------------------------
// GAT encoder: x --GATConv(2 heads,128)--> ELU --> {GATConv mu, GATConv ls}
// N=50000, E=800000 (+self loops). fp32 in/out. Edges int32 w/ int64 detect.
// Round 14:
//  * k_agg6: MERGE the column-half split (R8 vestige; its premise -- fetch
//    reduction matters -- was falsified in R9). One 32-lane group per node
//    covers all 256 cols at 16B/lane (dwordx4 gathers). Per edge: 1 gather
//    instr (was 2x8B), 1 csr+wp load (was 2), denom once (was 2). Wave count
//    halves; in-flight bytes/wave double. Cache-line touches identical ->
//    cleanly discriminates issue/latency-bound (time drops) vs
//    L1-line-throughput-bound (unchanged).
//  * Loop shape: R12 8/4/1 tails (best measured 63.6; R13 masking regressed).
//  * GEMM (M_rep=2 pipelined), k_w planes, CSR build unchanged (R12/R13).
// ---------------------------------------------------------------------------

typedef unsigned short u16;
typedef unsigned int u32;
typedef _Float16 f16;
typedef f16 f16x8 __attribute__((ext_vector_type(8)));
typedef float f32x4v __attribute__((ext_vector_type(4)));

__device__ __forceinline__ u16 f2h(float f) {
    union { f16 h; u16 u; } t;
    t.h = (f16)f;
    return t.u;
}
// 8 fp16 channels -> 8 floats (one dwordx4 load)
__device__ __forceinline__ void loadh8(const u16* __restrict__ p, size_t i,
                                       float* __restrict__ o) {
    union { uint4 u; f16 h[8]; } t;
    t.u = *(const uint4*)(p + i);
#pragma unroll
    for (int j = 0; j < 8; j++) o[j] = (float)t.h[j];
}
__device__ __forceinline__ void store4(float* __restrict__ p, size_t i, float4 v) {
    *(float4*)(p + i) = v;
}

// ---------------- edge normalize (+int64 detect, +degree count) --------------
__global__ __launch_bounds__(256) void k_extract(const u32* __restrict__ ebuf, int E,
                                                 int* __restrict__ se,
                                                 int* __restrict__ de,
                                                 int* __restrict__ deg) {
    __shared__ int nz;
    if (threadIdx.x == 0) nz = 0;
    __syncthreads();
    if (ebuf[2 * threadIdx.x + 1] != 0u) atomicAdd(&nz, 1);
    __syncthreads();
    const bool i64 = (nz == 0);
    int e = blockIdx.x * 256 + threadIdx.x;
    if (e >= E) return;
    int s, d;
    if (i64) {  // int64 layout
        s = (int)ebuf[2 * (size_t)e];
        d = (int)ebuf[2 * ((size_t)E + (size_t)e)];
    } else {  // int32 layout
        s = (int)ebuf[e];
        d = (int)ebuf[(size_t)E + (size_t)e];
    }
    se[e] = s;
    de[e] = d;
    atomicAdd(&deg[d], 1);
}

// ---------------- CSR build ----------------
__global__ __launch_bounds__(256) void k_scan_a(const int* __restrict__ deg, int n,
                                                int* __restrict__ bsum) {
    __shared__ int s[256];
    int i = blockIdx.x * 256 + threadIdx.x;
    s[threadIdx.x] = (i < n) ? deg[i] : 0;
    __syncthreads();
    for (int st = 128; st > 0; st >>= 1) {
        if (threadIdx.x < st) s[threadIdx.x] += s[threadIdx.x + st];
        __syncthreads();
    }
    if (threadIdx.x == 0) bsum[blockIdx.x] = s[0];
}

__global__ __launch_bounds__(256) void k_scan_b(int* __restrict__ bsum, int nb) {
    __shared__ int s[256];
    int t = threadIdx.x;
    int v = (t < nb) ? bsum[t] : 0;
    s[t] = v;
    __syncthreads();
    for (int off = 1; off < 256; off <<= 1) {
        int add = (t >= off) ? s[t - off] : 0;
        __syncthreads();
        s[t] += add;
        __syncthreads();
    }
    if (t < nb) bsum[t] = s[t] - v;  // exclusive
}

__global__ __launch_bounds__(256) void k_scan_c(const int* __restrict__ deg, int n,
                                                const int* __restrict__ bsum,
                                                int* __restrict__ rowptr,
                                                int* __restrict__ cursor, int E) {
    __shared__ int s[256];
    int t = threadIdx.x;
    int i = blockIdx.x * 256 + t;
    int v = (i < n) ? deg[i] : 0;
    s[t] = v;
    __syncthreads();
    for (int off = 1; off < 256; off <<= 1) {
        int add = (t >= off) ? s[t - off] : 0;
        __syncthreads();
        s[t] += add;
        __syncthreads();
    }
    if (i < n) {
        int ex = bsum[blockIdx.x] + s[t] - v;
        rowptr[i] = ex;
        cursor[i] = ex;
    }
    if (i == 0) rowptr[n] = E;
}

__global__ __launch_bounds__(256) void k_fill(const int* __restrict__ src,
                                              const int* __restrict__ dst, int E,
                                              int* __restrict__ cursor,
                                              int* __restrict__ csr_src,
                                              int* __restrict__ csr_dst) {
    int e = blockIdx.x * 256 + threadIdx.x;
    if (e < 8) csr_src[E + e] = 0;  // pad (safe over-read margin)
    if (e < E) {
        int d = dst[e];
        int slot = atomicAdd(&cursor[d], 1);
        csr_src[slot] = src[e];
        csr_dst[slot] = d;
    }
}

// Wt[c][k] = W[k][c] as fp16.  split==256: single W (row stride 256);
// split==128: c<128 from Wl, else Wr (row stride 128).
__global__ __launch_bounds__(256) void k_tw(const float* __restrict__ Wl,
                                            const float* __restrict__ Wr, int split,
                                            int K, u16* __restrict__ Wt) {
    int idx = blockIdx.x * 256 + threadIdx.x;
    if (idx >= 256 * K) return;
    int c = idx / K, k = idx - c * K;
    float v;
    if (split == 256)
        v = Wl[(size_t)k * 256 + c];
    else
        v = (c < 128) ? Wl[(size_t)k * 128 + c] : Wr[(size_t)k * 128 + (c - 128)];
    Wt[idx] = f2h(v);
}

// ---------------- edge-weight precompute (CSR order, per-slot planes) --------
// Plane stride Ep = E+8.
template <int NS>
__global__ __launch_bounds__(256) void k_w(const int* __restrict__ csr_src,
                                           const int* __restrict__ csr_dst,
                                           const float* __restrict__ as,
                                           const float* __restrict__ ad,
                                           float* __restrict__ wp, int E, int Ep) {
    int i = blockIdx.x * 256 + threadIdx.x;
    if (i >= E) return;
    int s = csr_src[i], d = csr_dst[i];
    if (NS == 2) {
        float2 a = *(const float2*)(as + (size_t)s * 2);
        float2 b = *(const float2*)(ad + (size_t)d * 2);
        float e0 = a.x + b.x, e1 = a.y + b.y;
        e0 = fmaxf(e0, 0.2f * e0);
        e1 = fmaxf(e1, 0.2f * e1);
        wp[i] = __expf(e0);
        wp[(size_t)Ep + i] = __expf(e1);
    } else {
        float4 a = *(const float4*)(as + (size_t)s * 4);
        float4 b = *(const float4*)(ad + (size_t)d * 4);
        float e0 = a.x + b.x, e1 = a.y + b.y, e2 = a.z + b.z, e3 = a.w + b.w;
        e0 = fmaxf(e0, 0.2f * e0);
        e1 = fmaxf(e1, 0.2f * e1);
        e2 = fmaxf(e2, 0.2f * e2);
        e3 = fmaxf(e3, 0.2f * e3);
        wp[i] = __expf(e0);
        wp[(size_t)Ep + i] = __expf(e1);
        wp[2 * (size_t)Ep + i] = __expf(e2);
        wp[3 * (size_t)Ep + i] = __expf(e3);
    }
}

// ---------------- MFMA GEMM + fused alpha epilogue --------------------------
// h[M,256](f16) = A[M,K] @ W[K,256]; Wt = W^T fp16 [256][K]. AF32: A is fp32
// (layer 1 reads x directly). M_rep=2: wave owns 32 rows (two A frags);
// each Bs ds_read_b128 feeds 2 MFMAs. Block = 4 waves = 128 rows. Software
// pipeline: next chunk's stage regs + A frags prefetched during MFMA; raw
// s_barrier with lgkmcnt(0)-only waits (global prefetches stay in flight).
template <int K, int ALOGW, bool AF32>
__global__ __launch_bounds__(256) void k_gemm_mfma(
    const void* __restrict__ Av, const u16* __restrict__ Wt, u16* __restrict__ out,
    float* __restrict__ as_out, float* __restrict__ ad_out,
    const float* __restrict__ alo, const float* __restrict__ ahi,
    const float* __restrict__ dlo, const float* __restrict__ dhi, int M) {
    __shared__ u16 Bs[256 * 40];  // 20KB
    const int tid = threadIdx.x;
    const int wave = tid >> 6;
    const int lane = tid & 63;
    const int li = lane & 15;
    const int quad = lane >> 4;
    const int r0 = blockIdx.x * 128 + wave * 32;
    int ar0 = r0 + li;
    int ar1 = r0 + 16 + li;
    if (ar0 >= M) ar0 = M - 1;  // clamp (stores are guarded)
    if (ar1 >= M) ar1 = M - 1;
    const u16* a16_0 = (const u16*)Av + (size_t)ar0 * K + quad * 8;
    const u16* a16_1 = (const u16*)Av + (size_t)ar1 * K + quad * 8;
    const float* a32_0 = (const float*)Av + (size_t)ar0 * K + quad * 8;
    const float* a32_1 = (const float*)Av + (size_t)ar1 * K + quad * 8;

    f32x4v acc0[16], acc1[16];
#pragma unroll
    for (int ct = 0; ct < 16; ct++) {
        acc0[ct] = (f32x4v)(0.f);
        acc1[ct] = (f32x4v)(0.f);
    }

    const u16* wrow = Wt + (size_t)tid * K;
    u16* dstp = Bs + tid * 40;
    // prologue prefetch (chunk 0)
    uint4 sv0 = ((const uint4*)wrow)[0];
    uint4 sv1 = ((const uint4*)(wrow + 8))[0];
    uint4 sv2 = ((const uint4*)(wrow + 16))[0];
    uint4 sv3 = ((const uint4*)(wrow + 24))[0];
    uint4 p0a, p0b, p1a, p1b;
    if (AF32) {
        p0a = *(const uint4*)(a32_0);
        p0b = *(const uint4*)(a32_0 + 4);
        p1a = *(const uint4*)(a32_1);
        p1b = *(const uint4*)(a32_1 + 4);
    } else {
        p0a = *(const uint4*)(a16_0);
        p1a = *(const uint4*)(a16_1);
        p0b = p0a;
        p1b = p1a;
    }

    for (int t = 0; t < K; t += 32) {
        asm volatile("s_waitcnt lgkmcnt(0)" ::: "memory");
        __builtin_amdgcn_s_barrier();  // Bs free for writing (prior reads done)
        ((uint4*)dstp)[0] = sv0;
        ((uint4*)(dstp + 8))[0] = sv1;
        ((uint4*)(dstp + 16))[0] = sv2;
        ((uint4*)(dstp + 24))[0] = sv3;
        f16x8 a0, a1;
        if (AF32) {
            union { uint4 u; float f[4]; } ua, ub;
            ua.u = p0a; ub.u = p0b;
            a0[0] = (f16)ua.f[0]; a0[1] = (f16)ua.f[1];
            a0[2] = (f16)ua.f[2]; a0[3] = (f16)ua.f[3];
            a0[4] = (f16)ub.f[0]; a0[5] = (f16)ub.f[1];
            a0[6] = (f16)ub.f[2]; a0[7] = (f16)ub.f[3];
            ua.u = p1a; ub.u = p1b;
            a1[0] = (f16)ua.f[0]; a1[1] = (f16)ua.f[1];
            a1[2] = (f16)ua.f[2]; a1[3] = (f16)ua.f[3];
            a1[4] = (f16)ub.f[0]; a1[5] = (f16)ub.f[1];
            a1[6] = (f16)ub.f[2]; a1[7] = (f16)ub.f[3];
        } else {
            union { uint4 u; f16x8 h; } uh;
            uh.u = p0a; a0 = uh.h;
            uh.u = p1a; a1 = uh.h;
        }
        if (t + 32 < K) {  // prefetch next chunk; stays in flight across barrier
            const u16* s2 = wrow + t + 32;
            sv0 = ((const uint4*)s2)[0];
            sv1 = ((const uint4*)(s2 + 8))[0];
            sv2 = ((const uint4*)(s2 + 16))[0];
            sv3 = ((const uint4*)(s2 + 24))[0];
            if (AF32) {
                p0a = *(const uint4*)(a32_0 + t + 32);
                p0b = *(const uint4*)(a32_0 + t + 36);
                p1a = *(const uint4*)(a32_1 + t + 32);
                p1b = *(const uint4*)(a32_1 + t + 36);
            } else {
                p0a = *(const uint4*)(a16_0 + t + 32);
                p1a = *(const uint4*)(a16_1 + t + 32);
            }
        }
        asm volatile("s_waitcnt lgkmcnt(0)" ::: "memory");
        __builtin_amdgcn_s_barrier();  // Bs ready (all ds_writes drained)
#pragma unroll
        for (int ct = 0; ct < 16; ct++) {
            f16x8 b = *(const f16x8*)(Bs + (ct * 16 + li) * 40 + quad * 8);
            acc0[ct] = __builtin_amdgcn_mfma_f32_16x16x32_f16(a0, b, acc0[ct], 0, 0, 0);
            acc1[ct] = __builtin_amdgcn_mfma_f32_16x16x32_f16(a1, b, acc1[ct], 0, 0, 0);
        }
    }

    const int NS = 64 >> ALOGW;   // 2 or 4
    const int SH = ALOGW - 2;     // slot = ct >> SH
    float aw[16], dw[16];
#pragma unroll
    for (int ct = 0; ct < 16; ct++) {
        int col = ct * 16 + li;
        aw[ct] = (col < 128) ? alo[col] : ahi[col - 128];
        dw[ct] = (col < 128) ? dlo[col] : dhi[col - 128];
    }

    auto epilogue = [&](f32x4v(&acc)[16], int rbase) {
        // h store (fp16): D row = quad*4+reg, col = ct*16+li
#pragma unroll
        for (int reg = 0; reg < 4; reg++) {
            int grow = rbase + quad * 4 + reg;
            if (grow < M) {
                u16* orow = out + (size_t)grow * 256 + li;
#pragma unroll
                for (int ct = 0; ct < 16; ct++) orow[ct * 16] = f2h(acc[ct][reg]);
            }
        }
        // fused alpha epilogue
#pragma unroll
        for (int reg = 0; reg < 4; reg++) {
            float s[4] = {0.f, 0.f, 0.f, 0.f};
            float d[4] = {0.f, 0.f, 0.f, 0.f};
#pragma unroll
            for (int ct = 0; ct < 16; ct++) {
                int sl = ct >> SH;
                s[sl] += acc[ct][reg] * aw[ct];
                d[sl] += acc[ct][reg] * dw[ct];
            }
#pragma unroll
            for (int sl = 0; sl < NS; sl++) {
#pragma unroll
                for (int m = 1; m <= 8; m <<= 1) {
                    s[sl] += __shfl_xor(s[sl], m, 64);
                    d[sl] += __shfl_xor(d[sl], m, 64);
                }
            }
            int grow = rbase + quad * 4 + reg;
            if (li == 0 && grow < M) {
#pragma unroll
                for (int sl = 0; sl < NS; sl++) {
                    as_out[(size_t)grow * NS + sl] = s[sl];
                    ad_out[(size_t)grow * NS + sl] = d[sl];
                }
            }
        }
    };
    epilogue(acc0, r0);
    epilogue(acc1, r0 + 16);
}

// ---------------- aggregation (softmax-weighted gather, full-row) ------------
// One 32-lane half-wave per dst node, covering ALL 256 cols: lane owns 8
// channels (16B dwordx4 gathers). Wave = 2 nodes. Per edge: 1 gather instr,
// 1 csr+wp load, denom once (the R8 column-half split processed each node
// twice; its fetch-affinity premise was falsified in R9). Weights from wp
// planes (slot = per-lane, lanes span NS slots). 8/4/1 loop (R12 shape).
// MODE 0: +bias, ELU, write fp16 x1 [n,256]. MODE 1: +bias, write fp32 mu/ls.
template <int LOGW, int MODE, typename OT>
__global__ __launch_bounds__(256) void k_agg6(
    const u16* __restrict__ h, const int* __restrict__ rowptr,
    const int* __restrict__ csr_src, const float* __restrict__ wp,
    const float* __restrict__ as, const float* __restrict__ ad,
    const float* __restrict__ b_lo, const float* __restrict__ b_hi,
    OT* __restrict__ outp, int n, int Ep) {
    const int NS = 64 >> LOGW;  // alpha slots (2 or 4)
    const int lane = threadIdx.x & 63;
    const int sub = lane >> 5;   // which node of the wave's pair
    const int sl = lane & 31;    // lane within the node
    const int wid0 = blockIdx.x * 8 + (threadIdx.x >> 6) * 2 + sub;
    const bool ok = wid0 < n;
    const int wid = ok ? wid0 : (n - 1);  // clamped for safe loads
    const int col = sl * 8;               // 8 channels per lane
    const int slot = col >> (LOGW + 2);
    const float* __restrict__ wpl = wp + (size_t)slot * Ep;

    // self-loop weight
    float e = as[(size_t)wid * NS + slot] + ad[(size_t)wid * NS + slot];
    e = fmaxf(e, 0.2f * e);  // LeakyReLU(0.2)
    float w = __expf(e);
    float denom = w;
    float acc[8], hb[8];
    loadh8(h, (size_t)wid * 256 + col, hb);
#pragma unroll
    for (int c = 0; c < 8; c++) acc[c] = w * hb[c];

    int rb = 0, re = 0;
    if (ok) { rb = rowptr[wid0]; re = rowptr[wid0 + 1]; }
    int p = rb;
    for (; p + 8 <= re; p += 8) {
        int4 sA = *(const int4*)(csr_src + p);
        int4 sB = *(const int4*)(csr_src + p + 4);
        float4 wA = *(const float4*)(wpl + p);
        float4 wB = *(const float4*)(wpl + p + 4);
        float h0[8], h1[8], h2[8], h3[8], h4[8], h5[8], h6[8], h7[8];
        loadh8(h, (size_t)sA.x * 256 + col, h0);
        loadh8(h, (size_t)sA.y * 256 + col, h1);
        loadh8(h, (size_t)sA.z * 256 + col, h2);
        loadh8(h, (size_t)sA.w * 256 + col, h3);
        loadh8(h, (size_t)sB.x * 256 + col, h4);
        loadh8(h, (size_t)sB.y * 256 + col, h5);
        loadh8(h, (size_t)sB.z * 256 + col, h6);
        loadh8(h, (size_t)sB.w * 256 + col, h7);
        denom += (wA.x + wA.y + wA.z + wA.w) + (wB.x + wB.y + wB.z + wB.w);
#pragma unroll
        for (int c = 0; c < 8; c++) {
            acc[c] += wA.x * h0[c] + wA.y * h1[c] + wA.z * h2[c] + wA.w * h3[c] +
                      wB.x * h4[c] + wB.y * h5[c] + wB.z * h6[c] + wB.w * h7[c];
        }
    }
    for (; p + 4 <= re; p += 4) {
        int4 sA = *(const int4*)(csr_src + p);
        float4 wA = *(const float4*)(wpl + p);
        float h0[8], h1[8], h2[8], h3[8];
        loadh8(h, (size_t)sA.x * 256 + col, h0);
        loadh8(h, (size_t)sA.y * 256 + col, h1);
        loadh8(h, (size_t)sA.z * 256 + col, h2);
        loadh8(h, (size_t)sA.w * 256 + col, h3);
        denom += (wA.x + wA.y) + (wA.z + wA.w);
#pragma unroll
        for (int c = 0; c < 8; c++) {
            acc[c] += wA.x * h0[c] + wA.y * h1[c] + wA.z * h2[c] + wA.w * h3[c];
        }
    }
    for (; p < re; ++p) {
        int s = csr_src[p];
        float ww = wpl[p];
        float hh[8];
        loadh8(h, (size_t)s * 256 + col, hh);
        denom += ww;
#pragma unroll
        for (int c = 0; c < 8; c++) acc[c] += ww * hh[c];
    }
    float inv = 1.0f / (denom + 1e-16f);

    // bias: cols 0-127 from b_lo, 128-255 from b_hi (8-col chunk never straddles)
    const float* bp = (sl < 16) ? (b_lo + col) : (b_hi + (col - 128));
    float v[8];
#pragma unroll
    for (int c = 0; c < 8; c++) v[c] = acc[c] * inv + bp[c];

    if (!ok) return;
    if (MODE == 0) {  // ELU -> x1 fp16 [n,256]
        union { uint4 u; f16 h[8]; } t;
#pragma unroll
        for (int c = 0; c < 8; c++) {
            float vv = v[c] > 0.f ? v[c] : expm1f(v[c]);
            t.h[c] = (f16)vv;
        }
        *(uint4*)((u16*)outp + (size_t)wid0 * 256 + col) = t.u;
    } else {  // cols 0-127 -> mu [n,128]; cols 128-255 -> logstd [n,128]
        size_t base = (sl < 16) ? ((size_t)wid0 * 128 + col)
                                : ((size_t)n * 128 + (size_t)wid0 * 128 + (col - 128));
        store4((float*)outp, base, make_float4(v[0], v[1], v[2], v[3]));
        store4((float*)outp, base + 4, make_float4(v[4], v[5], v[6], v[7]));
    }
}

// ---------------------------------------------------------------------------
extern "C" void kernel_launch(void* const* d_in, const int* in_sizes, int n_in,
                              void* d_out, int out_size, void* d_ws, size_t ws_size,
                              hipStream_t stream) {
    const float* x = (const float*)d_in[0];
    const u32* ebuf = (const u32*)d_in[1];
    const float* W1 = (const float*)d_in[2];
    const float* a_src1 = (const float*)d_in[3];
    const float* a_dst1 = (const float*)d_in[4];
    const float* b1 = (const float*)d_in[5];
    const float* W_mu = (const float*)d_in[6];
    const float* a_src_mu = (const float*)d_in[7];
    const float* a_dst_mu = (const float*)d_in[8];
    const float* b_mu = (const float*)d_in[9];
    const float* W_ls = (const float*)d_in[10];
    const float* a_src_ls = (const float*)d_in[11];
    const float* a_dst_ls = (const float*)d_in[12];
    const float* b_ls = (const float*)d_in[13];

    const int n = in_sizes[0] / 128;  // 50000
    const int E = in_sizes[1] / 2;    // 800000
    const int Ep = E + 8;             // padded csr/wp stride

    char* base = (char*)d_ws;
    size_t off = 0;
    auto alloc = [&](size_t b) -> char* {
        char* p = base + off;
        off = (off + b + 255) & ~(size_t)255;
        return p;
    };
    int* rowptr = (int*)alloc((size_t)(n + 1) * 4);
    int* cursor = (int*)alloc((size_t)n * 4);
    int* csr = (int*)alloc((size_t)Ep * 4);
    int* csrd = (int*)alloc((size_t)E * 4);
    int* bsum = (int*)alloc(256 * 4);
    int* se = (int*)alloc((size_t)E * 4);
    int* de = (int*)alloc((size_t)E * 4);
    float* as = (float*)alloc((size_t)n * 4 * 4);
    float* ad = (float*)alloc((size_t)n * 4 * 4);
    float* wp = (float*)alloc((size_t)Ep * 4 * 4);  // edge-weight planes (<=4)
    u16* W1t = (u16*)alloc(256 * 128 * 2);        // W1^T fp16 [256][128]
    u16* Wt2 = (u16*)alloc(256 * 256 * 2);        // [W_mu|W_ls]^T fp16 [256][256]
    u16* x1h = (u16*)alloc((size_t)n * 256 * 2);  // x1 fp16 [n,256]
    u16* h = (u16*)alloc((size_t)n * 256 * 2);    // h fp16 (both layers)

    const int nb = (n + 255) / 256;
    const int eg = (E + 255) / 256;
    const int gg = (n + 127) / 128;               // 128 rows per GEMM block
    const int aggGrid = (n + 7) / 8;              // 8 nodes per block

    // edge normalize + CSR build (reused by all three convs)
    hipMemsetAsync(cursor, 0, (size_t)n * 4, stream);
    k_extract<<<eg, 256, 0, stream>>>(ebuf, E, se, de, cursor);
    k_scan_a<<<nb, 256, 0, stream>>>(cursor, n, bsum);
    k_scan_b<<<1, 256, 0, stream>>>(bsum, nb);
    k_scan_c<<<nb, 256, 0, stream>>>(cursor, n, bsum, rowptr, cursor, E);
    k_fill<<<eg, 256, 0, stream>>>(se, de, E, cursor, csr, csrd);

    // weight transposes (fp16)
    k_tw<<<(256 * 128 + 255) / 256, 256, 0, stream>>>(W1, W1, 256, 128, W1t);
    k_tw<<<(256 * 256 + 255) / 256, 256, 0, stream>>>(W_mu, W_ls, 128, 256, Wt2);

    // Layer 1: h = x@W1 (MFMA, fp32 A, fused alphas); w planes; aggregate
    k_gemm_mfma<128, 5, true><<<gg, 256, 0, stream>>>(x, W1t, h, as, ad, a_src1,
                                                      a_src1 + 128, a_dst1,
                                                      a_dst1 + 128, n);
    k_w<2><<<eg, 256, 0, stream>>>(csr, csrd, as, ad, wp, E, Ep);
    k_agg6<5, 0, u16><<<aggGrid, 256, 0, stream>>>(h, rowptr, csr, wp, as, ad, b1,
                                                   b1 + 128, x1h, n, Ep);

    // Layers mu & ls: h = x1@[W_mu|W_ls] (MFMA, fused alphas); w; aggregate
    k_gemm_mfma<256, 4, false><<<gg, 256, 0, stream>>>(x1h, Wt2, h, as, ad,
                                                       a_src_mu, a_src_ls,
                                                       a_dst_mu, a_dst_ls, n);
    k_w<4><<<eg, 256, 0, stream>>>(csr, csrd, as, ad, wp, E, Ep);
    k_agg6<4, 1, float><<<aggGrid, 256, 0, stream>>>(h, rowptr, csr, wp, as, ad,
                                                     b_mu, b_ls, (float*)d_out, n,
                                                     Ep);
}